// Round 1
// baseline (190.138 us; speedup 1.0000x reference)
//
#include <hip/hip_runtime.h>

// EdgeSampler: one-hop neighbor sampling with replacement over CSR adjacency.
// Inputs (setup_inputs order):
//   d_in[0] source_node_ids  int32   [256*512]        = 131072
//   d_in[1] row_ptr          int32   [1000001]
//   d_in[2] col_indices      int32   [~32M]
//   d_in[3] rand_u           float32 [256*512*16]     = 2097152
// Output (tuple concatenated flat, int32):
//   d_out[0        .. 2097151]  src   (seed broadcast)
//   d_out[2097152  .. 4194303]  tgt   (sampled neighbor; col_indices[0] when deg==0)
//   d_out[4194304  .. 6291455]  valid (deg>0 ? 1 : 0)

#define NUM_SAMPLES (256 * 512 * 16)   // 2,097,152

__global__ __launch_bounds__(256) void EdgeSampler_62947040690666_kernel(
    const int* __restrict__ src_ids,    // [B*R]
    const int* __restrict__ row_ptr,    // [N+1]
    const int* __restrict__ col_idx,    // [E]
    const float* __restrict__ rand_u,   // [B*R*S]
    int* __restrict__ out_src,
    int* __restrict__ out_tgt,
    int* __restrict__ out_valid)
{
    int tid = blockIdx.x * blockDim.x + threadIdx.x;
    if (tid >= NUM_SAMPLES) return;

    // 16 consecutive threads share one seed -> row_ptr loads broadcast from L1.
    int seed_idx = tid >> 4;
    int seed  = src_ids[seed_idx];
    int start = row_ptr[seed];
    int deg   = row_ptr[seed + 1] - start;

    // Match reference fp32 arithmetic exactly: trunc(u * (float)deg), clamped.
    float u  = rand_u[tid];
    int idx  = (int)(u * (float)deg);
    int hi   = deg - 1;
    if (hi < 0) hi = 0;
    if (idx > hi) idx = hi;

    bool valid = (deg > 0);
    int pos = valid ? (start + idx) : 0;   // reference gathers col_indices[0] when invalid

    out_src[tid]   = seed;
    out_tgt[tid]   = col_idx[pos];
    out_valid[tid] = valid ? 1 : 0;
}

extern "C" void kernel_launch(void* const* d_in, const int* in_sizes, int n_in,
                              void* d_out, int out_size, void* d_ws, size_t ws_size,
                              hipStream_t stream) {
    const int*   src_ids = (const int*)d_in[0];
    const int*   row_ptr = (const int*)d_in[1];
    const int*   col_idx = (const int*)d_in[2];
    const float* rand_u  = (const float*)d_in[3];

    int* out = (int*)d_out;
    int* out_src   = out;
    int* out_tgt   = out + NUM_SAMPLES;
    int* out_valid = out + 2 * NUM_SAMPLES;

    const int block = 256;
    const int grid  = (NUM_SAMPLES + block - 1) / block;   // 8192 blocks
    EdgeSampler_62947040690666_kernel<<<grid, block, 0, stream>>>(
        src_ids, row_ptr, col_idx, rand_u, out_src, out_tgt, out_valid);
}

// Round 3
// 184.955 us; speedup vs baseline: 1.0280x; 1.0280x over previous
//
#include <hip/hip_runtime.h>

// EdgeSampler: one-hop neighbor sampling with replacement over CSR adjacency.
// Inputs (setup_inputs order):
//   d_in[0] source_node_ids  int32   [256*512]        = 131072
//   d_in[1] row_ptr          int32   [1000001]
//   d_in[2] col_indices      int32   [~32M]
//   d_in[3] rand_u           float32 [256*512*16]     = 2097152
// Output (tuple concatenated flat, int32):
//   d_out[0        .. 2097151]  src   (seed broadcast)
//   d_out[2097152  .. 4194303]  tgt   (sampled neighbor; col_indices[0] when deg==0)
//   d_out[4194304  .. 6291455]  valid (deg>0 ? 1 : 0)
//
// R3: same as R2 but with clang ext_vector_type for the nontemporal int4
// stores (HIP_vector_type int4 is a class — the builtin rejects it).

#define NUM_SAMPLES (256 * 512 * 16)           // 2,097,152
#define NUM_THREADS (NUM_SAMPLES / 4)          // 524,288

typedef int   vint4   __attribute__((ext_vector_type(4)));
typedef float vfloat4 __attribute__((ext_vector_type(4)));

__global__ __launch_bounds__(256) void EdgeSampler_62947040690666_kernel(
    const int* __restrict__ src_ids,      // [B*R]
    const int* __restrict__ row_ptr,      // [N+1]
    const int* __restrict__ col_idx,      // [E]
    const vfloat4* __restrict__ rand4,    // [B*R*S/4]
    vint4* __restrict__ out_src,
    vint4* __restrict__ out_tgt,
    vint4* __restrict__ out_valid)
{
    int tid = blockIdx.x * blockDim.x + threadIdx.x;   // grid sized exactly

    // 4 consecutive threads share one seed -> L1-broadcast row_ptr loads.
    int seed_idx = tid >> 2;
    int seed  = src_ids[seed_idx];
    int start = row_ptr[seed];
    int deg   = row_ptr[seed + 1] - start;

    vfloat4 u = rand4[tid];
    float degf = (float)deg;
    int hi = deg - 1; if (hi < 0) hi = 0;

    int i0 = (int)(u.x * degf); if (i0 > hi) i0 = hi;
    int i1 = (int)(u.y * degf); if (i1 > hi) i1 = hi;
    int i2 = (int)(u.z * degf); if (i2 > hi) i2 = hi;
    int i3 = (int)(u.w * degf); if (i3 > hi) i3 = hi;

    bool valid = (deg > 0);
    int base = valid ? start : 0;   // deg==0: reference gathers col_indices[0]
    // (when invalid, i0..i3 clamp to hi=0, so pos = base = 0)

    // 4 independent gathers — MLP within one thread.
    int t0 = col_idx[base + i0];
    int t1 = col_idx[base + i1];
    int t2 = col_idx[base + i2];
    int t3 = col_idx[base + i3];

    int v = valid ? 1 : 0;
    vint4 vsrc = (vint4){seed, seed, seed, seed};
    vint4 vtgt = (vint4){t0, t1, t2, t3};
    vint4 vval = (vint4){v, v, v, v};

    // Non-temporal: outputs are write-once; keep L2/L3 for col_idx lines.
    __builtin_nontemporal_store(vsrc, &out_src[tid]);
    __builtin_nontemporal_store(vtgt, &out_tgt[tid]);
    __builtin_nontemporal_store(vval, &out_valid[tid]);
}

extern "C" void kernel_launch(void* const* d_in, const int* in_sizes, int n_in,
                              void* d_out, int out_size, void* d_ws, size_t ws_size,
                              hipStream_t stream) {
    const int*     src_ids = (const int*)d_in[0];
    const int*     row_ptr = (const int*)d_in[1];
    const int*     col_idx = (const int*)d_in[2];
    const vfloat4* rand4   = (const vfloat4*)d_in[3];

    int* out = (int*)d_out;
    vint4* out_src   = (vint4*)(out);
    vint4* out_tgt   = (vint4*)(out + NUM_SAMPLES);
    vint4* out_valid = (vint4*)(out + 2 * NUM_SAMPLES);

    const int block = 256;
    const int grid  = NUM_THREADS / block;   // 2048 blocks, exact
    EdgeSampler_62947040690666_kernel<<<grid, block, 0, stream>>>(
        src_ids, row_ptr, col_idx, rand4, out_src, out_tgt, out_valid);
}

// Round 4
// 184.525 us; speedup vs baseline: 1.0304x; 1.0023x over previous
//
#include <hip/hip_runtime.h>

// EdgeSampler: one-hop neighbor sampling with replacement over CSR adjacency.
// Inputs (setup_inputs order):
//   d_in[0] source_node_ids  int32   [256*512]        = 131072
//   d_in[1] row_ptr          int32   [1000001]
//   d_in[2] col_indices      int32   [~32M]
//   d_in[3] rand_u           float32 [256*512*16]     = 2097152
// Output (tuple concatenated flat, int32):
//   d_out[0        .. 2097151]  src   (seed broadcast)
//   d_out[2097152  .. 4194303]  tgt   (sampled neighbor; col_indices[0] when deg==0)
//   d_out[4194304  .. 6291455]  valid (deg>0 ? 1 : 0)
//
// R4: R3 + non-temporal rand_u loads (streaming, zero reuse) so L2/L3 keep
// the col_indices gather lines — the only data with reuse. Per-sample VMEM
// is at its floor: 1 gather dword + 12 B coalesced nt stores + 4 B nt load.

#define NUM_SAMPLES (256 * 512 * 16)           // 2,097,152
#define NUM_THREADS (NUM_SAMPLES / 4)          // 524,288

typedef int   vint4   __attribute__((ext_vector_type(4)));
typedef float vfloat4 __attribute__((ext_vector_type(4)));

__global__ __launch_bounds__(256) void EdgeSampler_62947040690666_kernel(
    const int* __restrict__ src_ids,      // [B*R]
    const int* __restrict__ row_ptr,      // [N+1]
    const int* __restrict__ col_idx,      // [E]
    const vfloat4* __restrict__ rand4,    // [B*R*S/4]
    vint4* __restrict__ out_src,
    vint4* __restrict__ out_tgt,
    vint4* __restrict__ out_valid)
{
    int tid = blockIdx.x * blockDim.x + threadIdx.x;   // grid sized exactly

    // 4 consecutive threads share one seed -> L1-broadcast row_ptr loads.
    int seed_idx = tid >> 2;
    int seed  = src_ids[seed_idx];
    int start = row_ptr[seed];
    int deg   = row_ptr[seed + 1] - start;

    // Streaming read — bypass cache retention (no reuse of rand_u).
    vfloat4 u = __builtin_nontemporal_load(&rand4[tid]);

    float degf = (float)deg;
    int hi = deg - 1; if (hi < 0) hi = 0;

    int i0 = (int)(u.x * degf); if (i0 > hi) i0 = hi;
    int i1 = (int)(u.y * degf); if (i1 > hi) i1 = hi;
    int i2 = (int)(u.z * degf); if (i2 > hi) i2 = hi;
    int i3 = (int)(u.w * degf); if (i3 > hi) i3 = hi;

    bool valid = (deg > 0);
    int base = valid ? start : 0;   // deg==0: reference gathers col_indices[0]
    // (when invalid, i0..i3 clamp to hi=0, so pos = base = 0)

    // 4 independent gathers — MLP within one thread; lists are L2/L3-hot.
    int t0 = col_idx[base + i0];
    int t1 = col_idx[base + i1];
    int t2 = col_idx[base + i2];
    int t3 = col_idx[base + i3];

    int v = valid ? 1 : 0;
    vint4 vsrc = (vint4){seed, seed, seed, seed};
    vint4 vtgt = (vint4){t0, t1, t2, t3};
    vint4 vval = (vint4){v, v, v, v};

    // Non-temporal: outputs are write-once; keep L2/L3 for col_idx lines.
    __builtin_nontemporal_store(vsrc, &out_src[tid]);
    __builtin_nontemporal_store(vtgt, &out_tgt[tid]);
    __builtin_nontemporal_store(vval, &out_valid[tid]);
}

extern "C" void kernel_launch(void* const* d_in, const int* in_sizes, int n_in,
                              void* d_out, int out_size, void* d_ws, size_t ws_size,
                              hipStream_t stream) {
    const int*     src_ids = (const int*)d_in[0];
    const int*     row_ptr = (const int*)d_in[1];
    const int*     col_idx = (const int*)d_in[2];
    const vfloat4* rand4   = (const vfloat4*)d_in[3];

    int* out = (int*)d_out;
    vint4* out_src   = (vint4*)(out);
    vint4* out_tgt   = (vint4*)(out + NUM_SAMPLES);
    vint4* out_valid = (vint4*)(out + 2 * NUM_SAMPLES);

    const int block = 256;
    const int grid  = NUM_THREADS / block;   // 2048 blocks, exact
    EdgeSampler_62947040690666_kernel<<<grid, block, 0, stream>>>(
        src_ids, row_ptr, col_idx, rand4, out_src, out_tgt, out_valid);
}